// Round 3
// baseline (360.404 us; speedup 1.0000x reference)
//
#include <hip/hip_runtime.h>
#include <hip/hip_bf16.h>
#include <math.h>

#define NRES 512
#define CS   384
#define CZ   128
#define NH   12

static constexpr float WL_F      = 0.57735026918962576f;   // sqrt(1/3)
static constexpr float HALF_WC_F = 0.11785113019775792f;   // 0.5*sqrt(2/(9*4))

// ---------------------------------------------------------------------------
// Kernel 1: projections. grid (6 kinds, 128 i-tiles of 4 rows), 256 threads.
// ---------------------------------------------------------------------------
__global__ __launch_bounds__(256) void k_proj(
    const float* __restrict__ s, const float* __restrict__ rots,
    const float* __restrict__ trans,
    const float* __restrict__ Wq, const float* __restrict__ Wk,
    const float* __restrict__ Wv, const float* __restrict__ Wqp,
    const float* __restrict__ Wkp, const float* __restrict__ Wvp,
    float* __restrict__ qh, float* __restrict__ kh, float* __restrict__ vh,
    float* __restrict__ qg, float* __restrict__ kg, float* __restrict__ vg)
{
    const int tid  = threadIdx.x;
    const int kind = blockIdx.x;
    const int i0   = blockIdx.y * 4;
    __shared__ float s_lds[4][CS];
    __shared__ float hp_lds[4][288];

    for (int idx = tid; idx < 4 * CS; idx += 256) {
        int r = idx / CS, c = idx % CS;
        s_lds[r][c] = s[(size_t)(i0 + r) * CS + c];
    }
    __syncthreads();

    const float* Wsel;
    int W;
    switch (kind) {
        case 0: Wsel = Wq;  W = 192; break;
        case 1: Wsel = Wk;  W = 192; break;
        case 2: Wsel = Wv;  W = 192; break;
        case 3: Wsel = Wqp; W = 144; break;
        case 4: Wsel = Wkp; W = 144; break;
        default: Wsel = Wvp; W = 288; break;
    }

    for (int col = tid; col < W; col += 256) {
        float acc[4] = {0.f, 0.f, 0.f, 0.f};
        #pragma unroll 8
        for (int c = 0; c < CS; ++c) {
            float w = Wsel[(size_t)c * W + col];
            #pragma unroll
            for (int r = 0; r < 4; ++r) acc[r] += s_lds[r][c] * w;
        }
        #pragma unroll
        for (int r = 0; r < 4; ++r) {
            int i = i0 + r;
            if (kind == 0)      qh[(size_t)i * 192 + col] = acc[r];
            else if (kind == 1) kh[(size_t)i * 192 + col] = acc[r];
            else if (kind == 2) vh[(size_t)i * 192 + col] = acc[r];
            else                hp_lds[r][col] = acc[r];
        }
    }
    if (kind < 3) return;
    __syncthreads();

    const int npts = (kind == 5) ? 384 : 192;
    const int ppr  = (kind == 5) ? 96 : 48;
    for (int t = tid; t < npts; t += 256) {
        const int r = t / ppr, pt = t % ppr;
        const int i = i0 + r;
        float R[9], T[3];
        #pragma unroll
        for (int k = 0; k < 9; ++k) R[k] = rots[(size_t)i * 9 + k];
        #pragma unroll
        for (int k = 0; k < 3; ++k) T[k] = trans[(size_t)i * 3 + k];
        const float* src = &hp_lds[r][pt * 3];
        float* dst;
        if (kind == 3)      dst = &qg[(size_t)i * 144 + pt * 3];
        else if (kind == 4) dst = &kg[(size_t)i * 144 + pt * 3];
        else                dst = &vg[(size_t)i * 288 + pt * 3];
        float v0 = src[0], v1 = src[1], v2 = src[2];
        #pragma unroll
        for (int x = 0; x < 3; ++x)
            dst[x] = R[x * 3 + 0] * v0 + R[x * 3 + 1] * v1 + R[x * 3 + 2] * v2 + T[x];
    }
}

// ---------------------------------------------------------------------------
// Kernel 2: flash attention chunk. grid (512 i, 4 jc), 256 threads.
// lt[j][20]: per-j probability row (12 heads, padded to 20 -> conflict-free
// for j-strided softmax AND float4-aligned for phase-C broadcast reads).
// Phase C: warps 0-1 = o_hat (4 head-groups x 32 d4, float4 z loads);
//          warps 2-3 = o / o_hp (one float4 column of vh/vg per thread).
// No cross-thread reduction: every accumulator lives in one thread.
// ---------------------------------------------------------------------------
__global__ __launch_bounds__(256) void k_flash(
    const float* __restrict__ z, const float* __restrict__ Wb,
    const float* __restrict__ gamma,
    const float* __restrict__ qh, const float* __restrict__ kh,
    const float* __restrict__ vh, const float* __restrict__ qg,
    const float* __restrict__ kg, const float* __restrict__ vg,
    float* __restrict__ part)
{
    const int i   = blockIdx.x;
    const int jc  = blockIdx.y;
    const int j0  = jc * 128;
    const int tid = threadIdx.x;

    __shared__ float q_lds[192];
    __shared__ float qg_lds[144];
    __shared__ float gam_lds[NH];
    __shared__ float pm[NH], ps[NH];
    __shared__ float wb_lds[CZ * NH];     // [c][h], 6 KB
    __shared__ float lt[128 * 20];        // 10 KB

    if (tid < 192) q_lds[tid]  = qh[(size_t)i * 192 + tid];
    if (tid < 144) qg_lds[tid] = qg[(size_t)i * 144 + tid];
    for (int idx = tid; idx < CZ * NH; idx += 256) wb_lds[idx] = Wb[idx];
    if (tid < NH) gam_lds[tid] = gamma[tid];
    __syncthreads();

    // ---- Phase A: logits; thread = (jl, p) ----
    {
        const int jl = tid >> 1, p = tid & 1;
        const int j  = j0 + jl;
        const float4* zrow = (const float4*)(z + ((size_t)i * NRES + j) * CZ);
        float b[NH];
        #pragma unroll
        for (int h = 0; h < NH; ++h) b[h] = 0.f;
        #pragma unroll 4
        for (int c4 = 0; c4 < 16; ++c4) {
            const float4 zv = zrow[p * 16 + c4];
            // channels c = p*64 + c4*4 + cc ; wb_lds[c*12 + h] as float4 triples
            const float4* wbp = (const float4*)&wb_lds[(p * 64 + c4 * 4) * 12];
            #pragma unroll
            for (int cc = 0; cc < 4; ++cc) {
                const float zc = (cc == 0) ? zv.x : (cc == 1) ? zv.y : (cc == 2) ? zv.z : zv.w;
                float4 w0 = wbp[cc * 3 + 0];
                float4 w1 = wbp[cc * 3 + 1];
                float4 w2 = wbp[cc * 3 + 2];
                b[0] += zc * w0.x; b[1] += zc * w0.y; b[2]  += zc * w0.z; b[3]  += zc * w0.w;
                b[4] += zc * w1.x; b[5] += zc * w1.y; b[6]  += zc * w1.z; b[7]  += zc * w1.w;
                b[8] += zc * w2.x; b[9] += zc * w2.y; b[10] += zc * w2.z; b[11] += zc * w2.w;
            }
        }
        #pragma unroll
        for (int h = 0; h < NH; ++h) b[h] += __shfl_xor(b[h], 1);

        const int h0 = p * 6;
        #pragma unroll
        for (int h3 = 0; h3 < 6; ++h3) {
            const int h = h0 + h3;
            const float4* kp = (const float4*)(kh + (size_t)j * 192 + h * 16);
            const float4* qp = (const float4*)(q_lds + h * 16);
            float as = 0.f;
            #pragma unroll
            for (int u = 0; u < 4; ++u) {
                float4 kv = kp[u], qv = qp[u];
                as += kv.x * qv.x + kv.y * qv.y + kv.z * qv.z + kv.w * qv.w;
            }
            const float4* kgp = (const float4*)(kg + (size_t)j * 144 + h * 12);
            const float4* qgp = (const float4*)(qg_lds + h * 12);
            float d2 = 0.f;
            #pragma unroll
            for (int u = 0; u < 3; ++u) {
                float4 av = qgp[u], bv = kgp[u];
                float dx = av.x - bv.x, dy = av.y - bv.y;
                float dz = av.z - bv.z, dw = av.w - bv.w;
                d2 += dx * dx + dy * dy + dz * dz + dw * dw;
            }
            lt[jl * 20 + h] = WL_F * (as * 0.25f + b[h] - HALF_WC_F * gam_lds[h] * d2);
        }
    }
    __syncthreads();

    // ---- Phase B: chunk softmax; 16 lanes per head; lt stride 20 = no 16-way ----
    if (tid < 192) {
        const int h = tid >> 4, s = tid & 15;
        float m = -1e30f;
        for (int j = s; j < 128; j += 16) m = fmaxf(m, lt[j * 20 + h]);
        #pragma unroll
        for (int o = 1; o < 16; o <<= 1) m = fmaxf(m, __shfl_xor(m, o));
        float sum = 0.f;
        for (int j = s; j < 128; j += 16) {
            float e = __expf(lt[j * 20 + h] - m);
            lt[j * 20 + h] = e;
            sum += e;
        }
        #pragma unroll
        for (int o = 1; o < 16; o <<= 1) sum += __shfl_xor(sum, o);
        if (s == 0) { pm[h] = m; ps[h] = sum; }
    }
    __syncthreads();

    // ---- Phase C: unnormalized partials, all in registers ----
    float* pb = part + ((size_t)i * 4 + jc) * 2048;
    if (tid < 128) {
        // o_hat: head-group g (3 heads), float4 column u
        const int g = tid >> 5, u = tid & 31;
        const int h0 = g * 3;
        float4 a0 = {0.f, 0.f, 0.f, 0.f}, a1 = a0, a2 = a0;
        const float4* zb = (const float4*)(z + ((size_t)i * NRES + j0) * CZ);
        for (int jj = 0; jj < 128; ++jj) {
            const float4 zv = zb[jj * 32 + u];
            const float p0 = lt[jj * 20 + h0];
            const float p1 = lt[jj * 20 + h0 + 1];
            const float p2 = lt[jj * 20 + h0 + 2];
            a0.x += p0 * zv.x; a0.y += p0 * zv.y; a0.z += p0 * zv.z; a0.w += p0 * zv.w;
            a1.x += p1 * zv.x; a1.y += p1 * zv.y; a1.z += p1 * zv.z; a1.w += p1 * zv.w;
            a2.x += p2 * zv.x; a2.y += p2 * zv.y; a2.z += p2 * zv.z; a2.w += p2 * zv.w;
        }
        float4* pb4 = (float4*)pb;
        pb4[(h0 + 0) * 32 + u] = a0;
        pb4[(h0 + 1) * 32 + u] = a1;
        pb4[(h0 + 2) * 32 + u] = a2;
    } else {
        const int t2 = tid - 128;
        if (t2 < 120) {
            int h;
            const float* base;
            int rstride;
            if (t2 < 48) { h = t2 >> 2;            base = vh + (size_t)j0 * 192 + t2 * 4;        rstride = 192; }
            else         { int cc = t2 - 48; h = cc / 6; base = vg + (size_t)j0 * 288 + cc * 4;  rstride = 288; }
            float4 acc = {0.f, 0.f, 0.f, 0.f};
            for (int jj = 0; jj < 128; ++jj) {
                const float4 v = *(const float4*)(base + (size_t)jj * rstride);
                const float p = lt[jj * 20 + h];
                acc.x += p * v.x; acc.y += p * v.y; acc.z += p * v.z; acc.w += p * v.w;
            }
            ((float4*)(pb + 1536))[t2] = acc;
        }
    }
    if (tid < NH) { pb[2016 + tid] = pm[tid]; pb[2028 + tid] = ps[tid]; }
}

// ---------------------------------------------------------------------------
// Kernel 3: combine 4 chunks -> cat row. grid 512, 256 threads.
// ---------------------------------------------------------------------------
__global__ __launch_bounds__(256) void k_combine(
    const float* __restrict__ part, const float* __restrict__ rots,
    const float* __restrict__ trans, float* __restrict__ cat)
{
    const int i   = blockIdx.x;
    const int tid = threadIdx.x;
    __shared__ float wgt[4][NH];
    __shared__ float ohp[288];

    const float* pb = part + (size_t)i * 4 * 2048;
    if (tid < NH) {
        const int h = tid;
        float m0 = pb[2016 + h], m1 = pb[2048 + 2016 + h];
        float m2 = pb[4096 + 2016 + h], m3 = pb[6144 + 2016 + h];
        float M = fmaxf(fmaxf(m0, m1), fmaxf(m2, m3));
        float w0 = __expf(m0 - M), w1 = __expf(m1 - M);
        float w2 = __expf(m2 - M), w3 = __expf(m3 - M);
        float S = w0 * pb[2028 + h] + w1 * pb[2048 + 2028 + h] +
                  w2 * pb[4096 + 2028 + h] + w3 * pb[6144 + 2028 + h];
        float inv = 1.0f / S;
        wgt[0][h] = w0 * inv; wgt[1][h] = w1 * inv;
        wgt[2][h] = w2 * inv; wgt[3][h] = w3 * inv;
    }
    __syncthreads();

    float* crow = cat + (size_t)i * 2112;
    for (int idx = tid; idx < 1536; idx += 256) {
        const int h = idx >> 7;
        float v = 0.f;
        #pragma unroll
        for (int c = 0; c < 4; ++c) v += pb[c * 2048 + idx] * wgt[c][h];
        crow[idx] = v;
    }
    if (tid < 192) {
        const int h = tid >> 4;
        float v = 0.f;
        #pragma unroll
        for (int c = 0; c < 4; ++c) v += pb[c * 2048 + 1536 + tid] * wgt[c][h];
        crow[1536 + tid] = v;
    }
    for (int e = tid; e < 288; e += 256) {
        const int h = e / 24;
        float v = 0.f;
        #pragma unroll
        for (int c = 0; c < 4; ++c) v += pb[c * 2048 + 1728 + e] * wgt[c][h];
        ohp[e] = v;
    }
    __syncthreads();

    if (tid < 96) {
        const int h = tid >> 3, p = tid & 7;
        float R[9];
        #pragma unroll
        for (int k = 0; k < 9; ++k) R[k] = rots[(size_t)i * 9 + k];
        float g0 = ohp[h * 24 + p * 3 + 0] - trans[(size_t)i * 3 + 0];
        float g1 = ohp[h * 24 + p * 3 + 1] - trans[(size_t)i * 3 + 1];
        float g2 = ohp[h * 24 + p * 3 + 2] - trans[(size_t)i * 3 + 2];
        float oy0 = R[0] * g0 + R[3] * g1 + R[6] * g2;
        float oy1 = R[1] * g0 + R[4] * g1 + R[7] * g2;
        float oy2 = R[2] * g0 + R[5] * g1 + R[8] * g2;
        crow[1728 + h * 24 + p * 3 + 0] = oy0;
        crow[1728 + h * 24 + p * 3 + 1] = oy1;
        crow[1728 + h * 24 + p * 3 + 2] = oy2;
        crow[2016 + h * 8 + p] = sqrtf(oy0 * oy0 + oy1 * oy1 + oy2 * oy2);
    }
}

// ---------------------------------------------------------------------------
// Kernel 4: out-proj partials. grid (3 ctile, 64 rtile, 3 ksplit of 704).
// ---------------------------------------------------------------------------
__global__ __launch_bounds__(256) void k_out(
    const float* __restrict__ cat, const float* __restrict__ Wout,
    float* __restrict__ opart)
{
    const int tid = threadIdx.x;
    const int cp  = tid & 63;
    const int qd  = tid >> 6;
    const int c0  = blockIdx.x * 128 + cp * 2;
    const int i0  = blockIdx.y * 8;
    const int k0  = blockIdx.z * 704;
    const int r0  = qd * 2, r1 = r0 + 1;
    __shared__ float lds[8][65];
    float a00 = 0.f, a01 = 0.f, a10 = 0.f, a11 = 0.f;
    for (int kc = k0; kc < k0 + 704; kc += 64) {
        __syncthreads();
        for (int idx = tid; idx < 512; idx += 256) {
            int r = idx >> 6, kk = idx & 63;
            lds[r][kk] = cat[(size_t)(i0 + r) * 2112 + kc + kk];
        }
        __syncthreads();
        #pragma unroll 8
        for (int kk = 0; kk < 64; ++kk) {
            const float2 w = *(const float2*)(Wout + (size_t)(kc + kk) * 384 + c0);
            float l0 = lds[r0][kk], l1 = lds[r1][kk];
            a00 += l0 * w.x; a01 += l0 * w.y;
            a10 += l1 * w.x; a11 += l1 * w.y;
        }
    }
    float* ob = opart + (size_t)blockIdx.z * 512 * 384;
    ob[(size_t)(i0 + r0) * 384 + c0]     = a00;
    ob[(size_t)(i0 + r0) * 384 + c0 + 1] = a01;
    ob[(size_t)(i0 + r1) * 384 + c0]     = a10;
    ob[(size_t)(i0 + r1) * 384 + c0 + 1] = a11;
}

// Kernel 5: reduce 3 k-partials + bias.
__global__ __launch_bounds__(256) void k_outred(
    const float* __restrict__ opart, const float* __restrict__ bout,
    float* __restrict__ out)
{
    const int e4 = blockIdx.x * 256 + threadIdx.x;
    const float4* p = (const float4*)opart;
    const float4 b = ((const float4*)bout)[e4 % 96];
    float4 v0 = p[e4], v1 = p[e4 + 49152], v2 = p[e4 + 98304];
    float4 r;
    r.x = v0.x + v1.x + v2.x + b.x;
    r.y = v0.y + v1.y + v2.y + b.y;
    r.z = v0.z + v1.z + v2.z + b.z;
    r.w = v0.w + v1.w + v2.w + b.w;
    ((float4*)out)[e4] = r;
}

// ---------------------------------------------------------------------------
extern "C" void kernel_launch(void* const* d_in, const int* in_sizes, int n_in,
                              void* d_out, int out_size, void* d_ws, size_t ws_size,
                              hipStream_t stream)
{
    const float* s_i   = (const float*)d_in[0];
    const float* z_ij  = (const float*)d_in[1];
    const float* rots  = (const float*)d_in[2];
    const float* trans = (const float*)d_in[3];
    const float* Wq    = (const float*)d_in[4];
    const float* Wk    = (const float*)d_in[5];
    const float* Wv    = (const float*)d_in[6];
    const float* Wqp   = (const float*)d_in[7];
    const float* Wkp   = (const float*)d_in[8];
    const float* Wvp   = (const float*)d_in[9];
    const float* Wb    = (const float*)d_in[10];
    const float* gamma = (const float*)d_in[11];
    const float* Wout  = (const float*)d_in[12];
    const float* bout  = (const float*)d_in[13];
    float* ws    = (float*)d_ws;
    float* qh    = ws;                  // 512*192
    float* kh    = qh + 98304;
    float* vh    = kh + 98304;
    float* qg    = vh + 98304;          // 512*144
    float* kg    = qg + 73728;
    float* vg    = kg + 73728;          // 512*288
    float* part  = vg + 147456;         // 512*4*2048
    float* cat   = part + 4194304;      // 512*2112
    float* opart = cat + 1081344;       // 3*512*384
    float* out   = (float*)d_out;

    hipLaunchKernelGGL(k_proj, dim3(6, 128), dim3(256), 0, stream,
                       s_i, rots, trans, Wq, Wk, Wv, Wqp, Wkp, Wvp,
                       qh, kh, vh, qg, kg, vg);
    hipLaunchKernelGGL(k_flash, dim3(512, 4), dim3(256), 0, stream,
                       z_ij, Wb, gamma, qh, kh, vh, qg, kg, vg, part);
    hipLaunchKernelGGL(k_combine, dim3(512), dim3(256), 0, stream,
                       part, rots, trans, cat);
    hipLaunchKernelGGL(k_out, dim3(3, 64, 3), dim3(256), 0, stream,
                       cat, Wout, opart);
    hipLaunchKernelGGL(k_outred, dim3(192), dim3(256), 0, stream,
                       opart, bout, out);
}

// Round 4
// 212.386 us; speedup vs baseline: 1.6969x; 1.6969x over previous
//
#include <hip/hip_runtime.h>
#include <hip/hip_bf16.h>
#include <math.h>

#define NRES 512
#define CS   384
#define CZ   128
#define NH   12
#define PW   1152   // packed projection width: 192*3 + 144*2 + 288

static constexpr float WL_F      = 0.57735026918962576f;   // sqrt(1/3)
static constexpr float HALF_WC_F = 0.11785113019775792f;   // 0.5*sqrt(2/(9*4))

// ---------------------------------------------------------------------------
// Kernel 0: pack 6 weight matrices into Wcat[384][1152].
// cols: [0,192) Wq | [192,384) Wk | [384,576) Wv | [576,720) Wqp |
//       [720,864) Wkp | [864,1152) Wvp
// ---------------------------------------------------------------------------
__global__ __launch_bounds__(256) void k_pack(
    const float* __restrict__ Wq, const float* __restrict__ Wk,
    const float* __restrict__ Wv, const float* __restrict__ Wqp,
    const float* __restrict__ Wkp, const float* __restrict__ Wvp,
    float* __restrict__ Wcat)
{
    const int c = blockIdx.x;
    for (int col = threadIdx.x; col < PW; col += 256) {
        float v;
        if (col < 192)      v = Wq [(size_t)c * 192 + col];
        else if (col < 384) v = Wk [(size_t)c * 192 + col - 192];
        else if (col < 576) v = Wv [(size_t)c * 192 + col - 384];
        else if (col < 720) v = Wqp[(size_t)c * 144 + col - 576];
        else if (col < 864) v = Wkp[(size_t)c * 144 + col - 720];
        else                v = Wvp[(size_t)c * 288 + col - 864];
        Wcat[(size_t)c * PW + col] = v;
    }
}

// ---------------------------------------------------------------------------
// Kernel 1: P[512][1152] = s (512x384) @ Wcat (384x1152), rigid transform
// fused into epilogue for cols >= 576 (each thread owns whole 3-vectors).
// BM=32, BN=96, BK=32; grid (12, 16); 256 threads; 2x6 micro-tile.
// ---------------------------------------------------------------------------
__global__ __launch_bounds__(256) void k_gemm(
    const float* __restrict__ s, const float* __restrict__ Wcat,
    const float* __restrict__ rots, const float* __restrict__ trans,
    float* __restrict__ P)
{
    const int tid = threadIdx.x;
    const int tx = tid & 15, ty = tid >> 4;
    const int n0 = blockIdx.x * 96;
    const int m0 = blockIdx.y * 32;
    __shared__ float As[32][34];     // [kk][row], pad 34 keeps float2 aligned
    __shared__ float Bs[32][98];     // [kk][col]
    __shared__ float rot_lds[32][12];

    if (n0 >= 576) {
        for (int idx = tid; idx < 32 * 12; idx += 256) {
            int r = idx / 12, q = idx % 12;
            rot_lds[r][q] = (q < 9) ? rots[(size_t)(m0 + r) * 9 + q]
                                    : trans[(size_t)(m0 + r) * 3 + q - 9];
        }
    }

    float acc[2][6];
    #pragma unroll
    for (int u = 0; u < 2; ++u)
        #pragma unroll
        for (int v = 0; v < 6; ++v) acc[u][v] = 0.f;

    for (int k0 = 0; k0 < CS; k0 += 32) {
        __syncthreads();
        #pragma unroll
        for (int l = 0; l < 4; ++l) {
            int idx = tid + l * 256;           // 1024 = 32 rows x 32 k
            int kk = idx & 31, r = idx >> 5;
            As[kk][r] = s[(size_t)(m0 + r) * CS + k0 + kk];
        }
        #pragma unroll
        for (int l = 0; l < 12; ++l) {
            int idx = tid + l * 256;           // 3072 = 32 k x 96 cols
            int kk = idx / 96, cc = idx % 96;
            Bs[kk][cc] = Wcat[(size_t)(k0 + kk) * PW + n0 + cc];
        }
        __syncthreads();
        #pragma unroll
        for (int kk = 0; kk < 32; ++kk) {
            const float2 a  = *(const float2*)&As[kk][ty * 2];
            const float2 b0 = *(const float2*)&Bs[kk][tx * 6];
            const float2 b1 = *(const float2*)&Bs[kk][tx * 6 + 2];
            const float2 b2 = *(const float2*)&Bs[kk][tx * 6 + 4];
            acc[0][0] += a.x * b0.x; acc[0][1] += a.x * b0.y;
            acc[0][2] += a.x * b1.x; acc[0][3] += a.x * b1.y;
            acc[0][4] += a.x * b2.x; acc[0][5] += a.x * b2.y;
            acc[1][0] += a.y * b0.x; acc[1][1] += a.y * b0.y;
            acc[1][2] += a.y * b1.x; acc[1][3] += a.y * b1.y;
            acc[1][4] += a.y * b2.x; acc[1][5] += a.y * b2.y;
        }
    }

    if (n0 >= 576) {
        // apply(): out[x] = sum_y R[x,y]*p[y] + T[x]; 2 points per row
        #pragma unroll
        for (int u = 0; u < 2; ++u) {
            const float* RT = rot_lds[ty * 2 + u];
            #pragma unroll
            for (int v = 0; v < 2; ++v) {
                float p0 = acc[u][v * 3], p1 = acc[u][v * 3 + 1], p2 = acc[u][v * 3 + 2];
                acc[u][v * 3 + 0] = RT[0] * p0 + RT[1] * p1 + RT[2] * p2 + RT[9];
                acc[u][v * 3 + 1] = RT[3] * p0 + RT[4] * p1 + RT[5] * p2 + RT[10];
                acc[u][v * 3 + 2] = RT[6] * p0 + RT[7] * p1 + RT[8] * p2 + RT[11];
            }
        }
    }
    #pragma unroll
    for (int u = 0; u < 2; ++u) {
        float* dst = P + (size_t)(m0 + ty * 2 + u) * PW + n0 + tx * 6;
        *(float2*)(dst)     = make_float2(acc[u][0], acc[u][1]);
        *(float2*)(dst + 2) = make_float2(acc[u][2], acc[u][3]);
        *(float2*)(dst + 4) = make_float2(acc[u][4], acc[u][5]);
    }
}

// ---------------------------------------------------------------------------
// Kernel 2: flash attention chunk. grid (512 i, 4 jc), 256 threads.
// P row i: [0,192) q | [192,384) k | [384,576) v | [576,720) qg |
//          [720,864) kg | [864,1152) vg   (stride 1152)
// ---------------------------------------------------------------------------
__global__ __launch_bounds__(256) void k_flash(
    const float* __restrict__ z, const float* __restrict__ Wb,
    const float* __restrict__ gamma, const float* __restrict__ P,
    float* __restrict__ part)
{
    const int i   = blockIdx.x;
    const int jc  = blockIdx.y;
    const int j0  = jc * 128;
    const int tid = threadIdx.x;

    __shared__ float q_lds[192];
    __shared__ float qg_lds[144];
    __shared__ float gam_lds[NH];
    __shared__ float pm[NH], ps[NH];
    __shared__ float wb_lds[CZ * NH];     // [c][h], 6 KB
    __shared__ float lt[128 * 20];        // 10 KB

    const float* qrow = P + (size_t)i * PW;
    if (tid < 192) q_lds[tid]  = qrow[tid];
    if (tid < 144) qg_lds[tid] = qrow[576 + tid];
    for (int idx = tid; idx < CZ * NH; idx += 256) wb_lds[idx] = Wb[idx];
    if (tid < NH) gam_lds[tid] = gamma[tid];
    __syncthreads();

    // ---- Phase A: logits; thread = (jl, p) ----
    {
        const int jl = tid >> 1, p = tid & 1;
        const int j  = j0 + jl;
        const float4* zrow = (const float4*)(z + ((size_t)i * NRES + j) * CZ);
        float b[NH];
        #pragma unroll
        for (int h = 0; h < NH; ++h) b[h] = 0.f;
        #pragma unroll 4
        for (int c4 = 0; c4 < 16; ++c4) {
            const float4 zv = zrow[p * 16 + c4];
            const float4* wbp = (const float4*)&wb_lds[(p * 64 + c4 * 4) * 12];
            #pragma unroll
            for (int cc = 0; cc < 4; ++cc) {
                const float zc = (cc == 0) ? zv.x : (cc == 1) ? zv.y : (cc == 2) ? zv.z : zv.w;
                float4 w0 = wbp[cc * 3 + 0];
                float4 w1 = wbp[cc * 3 + 1];
                float4 w2 = wbp[cc * 3 + 2];
                b[0] += zc * w0.x; b[1] += zc * w0.y; b[2]  += zc * w0.z; b[3]  += zc * w0.w;
                b[4] += zc * w1.x; b[5] += zc * w1.y; b[6]  += zc * w1.z; b[7]  += zc * w1.w;
                b[8] += zc * w2.x; b[9] += zc * w2.y; b[10] += zc * w2.z; b[11] += zc * w2.w;
            }
        }
        #pragma unroll
        for (int h = 0; h < NH; ++h) b[h] += __shfl_xor(b[h], 1);

        const int h0 = p * 6;
        #pragma unroll
        for (int h3 = 0; h3 < 6; ++h3) {
            const int h = h0 + h3;
            const float4* kp = (const float4*)(P + (size_t)j * PW + 192 + h * 16);
            const float4* qp = (const float4*)(q_lds + h * 16);
            float as = 0.f;
            #pragma unroll
            for (int u = 0; u < 4; ++u) {
                float4 kv = kp[u], qv = qp[u];
                as += kv.x * qv.x + kv.y * qv.y + kv.z * qv.z + kv.w * qv.w;
            }
            const float4* kgp = (const float4*)(P + (size_t)j * PW + 720 + h * 12);
            const float4* qgp = (const float4*)(qg_lds + h * 12);
            float d2 = 0.f;
            #pragma unroll
            for (int u = 0; u < 3; ++u) {
                float4 av = qgp[u], bv = kgp[u];
                float dx = av.x - bv.x, dy = av.y - bv.y;
                float dz = av.z - bv.z, dw = av.w - bv.w;
                d2 += dx * dx + dy * dy + dz * dz + dw * dw;
            }
            lt[jl * 20 + h] = WL_F * (as * 0.25f + b[h] - HALF_WC_F * gam_lds[h] * d2);
        }
    }
    __syncthreads();

    // ---- Phase B: chunk softmax; 16 lanes per head ----
    if (tid < 192) {
        const int h = tid >> 4, s = tid & 15;
        float m = -1e30f;
        for (int j = s; j < 128; j += 16) m = fmaxf(m, lt[j * 20 + h]);
        #pragma unroll
        for (int o = 1; o < 16; o <<= 1) m = fmaxf(m, __shfl_xor(m, o));
        float sum = 0.f;
        for (int j = s; j < 128; j += 16) {
            float e = __expf(lt[j * 20 + h] - m);
            lt[j * 20 + h] = e;
            sum += e;
        }
        #pragma unroll
        for (int o = 1; o < 16; o <<= 1) sum += __shfl_xor(sum, o);
        if (s == 0) { pm[h] = m; ps[h] = sum; }
    }
    __syncthreads();

    // ---- Phase C: unnormalized partials, all in registers ----
    float* pb = part + ((size_t)i * 4 + jc) * 2048;
    if (tid < 128) {
        const int g = tid >> 5, u = tid & 31;
        const int h0 = g * 3;
        float4 a0 = {0.f, 0.f, 0.f, 0.f}, a1 = a0, a2 = a0;
        const float4* zb = (const float4*)(z + ((size_t)i * NRES + j0) * CZ);
        for (int jj = 0; jj < 128; ++jj) {
            const float4 zv = zb[jj * 32 + u];
            const float p0 = lt[jj * 20 + h0];
            const float p1 = lt[jj * 20 + h0 + 1];
            const float p2 = lt[jj * 20 + h0 + 2];
            a0.x += p0 * zv.x; a0.y += p0 * zv.y; a0.z += p0 * zv.z; a0.w += p0 * zv.w;
            a1.x += p1 * zv.x; a1.y += p1 * zv.y; a1.z += p1 * zv.z; a1.w += p1 * zv.w;
            a2.x += p2 * zv.x; a2.y += p2 * zv.y; a2.z += p2 * zv.z; a2.w += p2 * zv.w;
        }
        float4* pb4 = (float4*)pb;
        pb4[(h0 + 0) * 32 + u] = a0;
        pb4[(h0 + 1) * 32 + u] = a1;
        pb4[(h0 + 2) * 32 + u] = a2;
    } else {
        const int t2 = tid - 128;
        if (t2 < 120) {
            int h;
            const float* base;
            if (t2 < 48) { h = t2 >> 2;              base = P + (size_t)j0 * PW + 384 + t2 * 4; }
            else         { int cc = t2 - 48; h = cc / 6; base = P + (size_t)j0 * PW + 864 + cc * 4; }
            float4 acc = {0.f, 0.f, 0.f, 0.f};
            for (int jj = 0; jj < 128; ++jj) {
                const float4 v = *(const float4*)(base + (size_t)jj * PW);
                const float p = lt[jj * 20 + h];
                acc.x += p * v.x; acc.y += p * v.y; acc.z += p * v.z; acc.w += p * v.w;
            }
            ((float4*)(pb + 1536))[t2] = acc;
        }
    }
    if (tid < NH) { pb[2016 + tid] = pm[tid]; pb[2028 + tid] = ps[tid]; }
}

// ---------------------------------------------------------------------------
// Kernel 3: combine 4 chunks -> cat row. grid 512, 256 threads.
// ---------------------------------------------------------------------------
__global__ __launch_bounds__(256) void k_combine(
    const float* __restrict__ part, const float* __restrict__ rots,
    const float* __restrict__ trans, float* __restrict__ cat)
{
    const int i   = blockIdx.x;
    const int tid = threadIdx.x;
    __shared__ float wgt[4][NH];
    __shared__ float ohp[288];

    const float* pb = part + (size_t)i * 4 * 2048;
    if (tid < NH) {
        const int h = tid;
        float m0 = pb[2016 + h], m1 = pb[2048 + 2016 + h];
        float m2 = pb[4096 + 2016 + h], m3 = pb[6144 + 2016 + h];
        float M = fmaxf(fmaxf(m0, m1), fmaxf(m2, m3));
        float w0 = __expf(m0 - M), w1 = __expf(m1 - M);
        float w2 = __expf(m2 - M), w3 = __expf(m3 - M);
        float S = w0 * pb[2028 + h] + w1 * pb[2048 + 2028 + h] +
                  w2 * pb[4096 + 2028 + h] + w3 * pb[6144 + 2028 + h];
        float inv = 1.0f / S;
        wgt[0][h] = w0 * inv; wgt[1][h] = w1 * inv;
        wgt[2][h] = w2 * inv; wgt[3][h] = w3 * inv;
    }
    __syncthreads();

    float* crow = cat + (size_t)i * 2112;
    for (int idx = tid; idx < 1536; idx += 256) {
        const int h = idx >> 7;
        float v = 0.f;
        #pragma unroll
        for (int c = 0; c < 4; ++c) v += pb[c * 2048 + idx] * wgt[c][h];
        crow[idx] = v;
    }
    if (tid < 192) {
        const int h = tid >> 4;
        float v = 0.f;
        #pragma unroll
        for (int c = 0; c < 4; ++c) v += pb[c * 2048 + 1536 + tid] * wgt[c][h];
        crow[1536 + tid] = v;
    }
    for (int e = tid; e < 288; e += 256) {
        const int h = e / 24;
        float v = 0.f;
        #pragma unroll
        for (int c = 0; c < 4; ++c) v += pb[c * 2048 + 1728 + e] * wgt[c][h];
        ohp[e] = v;
    }
    __syncthreads();

    if (tid < 96) {
        const int h = tid >> 3, p = tid & 7;
        float R[9];
        #pragma unroll
        for (int k = 0; k < 9; ++k) R[k] = rots[(size_t)i * 9 + k];
        float g0 = ohp[h * 24 + p * 3 + 0] - trans[(size_t)i * 3 + 0];
        float g1 = ohp[h * 24 + p * 3 + 1] - trans[(size_t)i * 3 + 1];
        float g2 = ohp[h * 24 + p * 3 + 2] - trans[(size_t)i * 3 + 2];
        float oy0 = R[0] * g0 + R[3] * g1 + R[6] * g2;
        float oy1 = R[1] * g0 + R[4] * g1 + R[7] * g2;
        float oy2 = R[2] * g0 + R[5] * g1 + R[8] * g2;
        crow[1728 + h * 24 + p * 3 + 0] = oy0;
        crow[1728 + h * 24 + p * 3 + 1] = oy1;
        crow[1728 + h * 24 + p * 3 + 2] = oy2;
        crow[2016 + h * 8 + p] = sqrtf(oy0 * oy0 + oy1 * oy1 + oy2 * oy2);
    }
}

// ---------------------------------------------------------------------------
// Kernel 4: out-proj partials. grid (3 ctile, 64 rtile, 3 ksplit of 704).
// ---------------------------------------------------------------------------
__global__ __launch_bounds__(256) void k_out(
    const float* __restrict__ cat, const float* __restrict__ Wout,
    float* __restrict__ opart)
{
    const int tid = threadIdx.x;
    const int cp  = tid & 63;
    const int qd  = tid >> 6;
    const int c0  = blockIdx.x * 128 + cp * 2;
    const int i0  = blockIdx.y * 8;
    const int k0  = blockIdx.z * 704;
    const int r0  = qd * 2, r1 = r0 + 1;
    __shared__ float lds[8][65];
    float a00 = 0.f, a01 = 0.f, a10 = 0.f, a11 = 0.f;
    for (int kc = k0; kc < k0 + 704; kc += 64) {
        __syncthreads();
        for (int idx = tid; idx < 512; idx += 256) {
            int r = idx >> 6, kk = idx & 63;
            lds[r][kk] = cat[(size_t)(i0 + r) * 2112 + kc + kk];
        }
        __syncthreads();
        #pragma unroll 8
        for (int kk = 0; kk < 64; ++kk) {
            const float2 w = *(const float2*)(Wout + (size_t)(kc + kk) * 384 + c0);
            float l0 = lds[r0][kk], l1 = lds[r1][kk];
            a00 += l0 * w.x; a01 += l0 * w.y;
            a10 += l1 * w.x; a11 += l1 * w.y;
        }
    }
    float* ob = opart + (size_t)blockIdx.z * 512 * 384;
    ob[(size_t)(i0 + r0) * 384 + c0]     = a00;
    ob[(size_t)(i0 + r0) * 384 + c0 + 1] = a01;
    ob[(size_t)(i0 + r1) * 384 + c0]     = a10;
    ob[(size_t)(i0 + r1) * 384 + c0 + 1] = a11;
}

// Kernel 5: reduce 3 k-partials + bias.
__global__ __launch_bounds__(256) void k_outred(
    const float* __restrict__ opart, const float* __restrict__ bout,
    float* __restrict__ out)
{
    const int e4 = blockIdx.x * 256 + threadIdx.x;
    const float4* p = (const float4*)opart;
    const float4 b = ((const float4*)bout)[e4 % 96];
    float4 v0 = p[e4], v1 = p[e4 + 49152], v2 = p[e4 + 98304];
    float4 r;
    r.x = v0.x + v1.x + v2.x + b.x;
    r.y = v0.y + v1.y + v2.y + b.y;
    r.z = v0.z + v1.z + v2.z + b.z;
    r.w = v0.w + v1.w + v2.w + b.w;
    ((float4*)out)[e4] = r;
}

// ---------------------------------------------------------------------------
extern "C" void kernel_launch(void* const* d_in, const int* in_sizes, int n_in,
                              void* d_out, int out_size, void* d_ws, size_t ws_size,
                              hipStream_t stream)
{
    const float* s_i   = (const float*)d_in[0];
    const float* z_ij  = (const float*)d_in[1];
    const float* rots  = (const float*)d_in[2];
    const float* trans = (const float*)d_in[3];
    const float* Wq    = (const float*)d_in[4];
    const float* Wk    = (const float*)d_in[5];
    const float* Wv    = (const float*)d_in[6];
    const float* Wqp   = (const float*)d_in[7];
    const float* Wkp   = (const float*)d_in[8];
    const float* Wvp   = (const float*)d_in[9];
    const float* Wb    = (const float*)d_in[10];
    const float* gamma = (const float*)d_in[11];
    const float* Wout  = (const float*)d_in[12];
    const float* bout  = (const float*)d_in[13];
    float* ws = (float*)d_ws;
    // Region A (589824 floats): Wcat (442368, written+read early) then
    // opart (589824, written+read late). Aliasing is safe: k_pack fully
    // rewrites Wcat each call before k_gemm reads it.
    float* wcat  = ws;
    float* opart = ws;
    float* P     = ws + 589824;         // 512*1152
    float* part  = P + 589824;          // 512*4*2048
    float* cat   = part + 4194304;      // 512*2112
    float* out   = (float*)d_out;

    hipLaunchKernelGGL(k_pack, dim3(384), dim3(256), 0, stream,
                       Wq, Wk, Wv, Wqp, Wkp, Wvp, wcat);
    hipLaunchKernelGGL(k_gemm, dim3(12, 16), dim3(256), 0, stream,
                       s_i, wcat, rots, trans, P);
    hipLaunchKernelGGL(k_flash, dim3(512, 4), dim3(256), 0, stream,
                       z_ij, Wb, gamma, P, part);
    hipLaunchKernelGGL(k_combine, dim3(512), dim3(256), 0, stream,
                       part, rots, trans, cat);
    hipLaunchKernelGGL(k_out, dim3(3, 64, 3), dim3(256), 0, stream,
                       cat, Wout, opart);
    hipLaunchKernelGGL(k_outred, dim3(192), dim3(256), 0, stream,
                       opart, bout, out);
}